// Round 7
// baseline (85.592 us; speedup 1.0000x reference)
//
#include <hip/hip_runtime.h>
#include <stdint.h>
#include <stddef.h>

// Problem constants (from the reference):
//   L_MAX=2, NU_MAX=3, K=8, Q=16, S=256
//   nu=2 tuples (6): rows [K,Q,Q]   = 2048 rows each, 6*2048  = 12288 rows
//   nu=3 tuples (10): rows [K,Q,Q,Q]= 32768 rows each, 10*32768 = 327680 rows
//   output = 339968 rows x 256 f32 = 87,031,808 f32 = 348 MB (write-bound)
//
// Work decomposition: "unit" = 16 output rows sharing one front factor
//   nu=2 unit (t,k,q1): rows over q2        -> 768 units
//   nu=3 unit (t,k,q1,q2): rows over q3     -> 20480 units
//   total 21248 units = 84992 quarter-units (4 rows / 4 KB each)
// 2048 waves (256 blocks x 512 thr = 1 block/CU, 332 quarters/CU exactly).
// Ping-pong prefetch: quarter i+1 loads issue BEFORE quarter i stores, so
// s_waitcnt before compute never waits on store drain (vmcnt in-order).
#define KK 8
#define QQ 16
#define SS 256
#define NU2_ROWS 12288u

typedef float f32x4 __attribute__((ext_vector_type(4)));

namespace {

// ---------- exact replication of numpy default_rng(0) ----------
struct NpPcg64 {
  unsigned __int128 state, inc;
  uint32_t uinteger;
  bool has_uint32;

  static unsigned __int128 mul128() {
    return (((unsigned __int128)2549297995355413924ULL) << 64) | 4865540595714422341ULL;
  }
  void step() { state = state * mul128() + inc; }
  uint64_t next64() {
    step();  // numpy pcg64: step THEN output (xsl-rr on new state)
    uint64_t hi = (uint64_t)(state >> 64), lo = (uint64_t)state;
    uint64_t x = hi ^ lo;
    unsigned rot = (unsigned)(state >> 122) & 63u;
    return (x >> rot) | (x << ((64u - rot) & 63u));
  }
  uint32_t next32() {
    if (has_uint32) { has_uint32 = false; return uinteger; }
    uint64_t n = next64();
    has_uint32 = true;
    uinteger = (uint32_t)(n >> 32);
    return (uint32_t)n;
  }
  double nextd() {
    return (double)(next64() >> 11) * (1.0 / 9007199254740992.0);
  }
  uint32_t lemire32(uint32_t rng) {
    uint32_t excl = rng + 1u;
    uint64_t m = (uint64_t)next32() * (uint64_t)excl;
    uint32_t leftover = (uint32_t)m;
    if (leftover < excl) {
      uint32_t threshold = (uint32_t)((0xFFFFFFFFu - rng) % excl);
      while (leftover < threshold) {
        m = (uint64_t)next32() * (uint64_t)excl;
        leftover = (uint32_t)m;
      }
    }
    return (uint32_t)(m >> 32);
  }
  void integers(int high, int* out, int n) {
    if (high <= 1) { for (int i = 0; i < n; i++) out[i] = 0; return; }
    uint32_t rng = (uint32_t)(high - 1);
    for (int i = 0; i < n; i++) out[i] = (int)lemire32(rng);
  }
  void mults(float* out, int n) {
    for (int i = 0; i < n; i++) out[i] = (float)(nextd() + 0.5);
  }
};

void seed_rng0(NpPcg64& r) {
  uint32_t pool[4];
  uint32_t hc = 0x43b0d7e5u;  // INIT_A
  auto hashmix = [&hc](uint32_t v) -> uint32_t {
    v ^= hc; hc *= 0x931e8875u; v *= hc; v ^= v >> 16; return v;
  };
  auto mix = [](uint32_t x, uint32_t y) -> uint32_t {
    uint32_t m = 0xca01f9ddu * x - 0x4973f715u * y; m ^= m >> 16; return m;
  };
  for (int i = 0; i < 4; i++) pool[i] = hashmix(0u);
  for (int is = 0; is < 4; is++)
    for (int id = 0; id < 4; id++)
      if (is != id) pool[id] = mix(pool[id], hashmix(pool[is]));
  uint32_t hb = 0x8b51f9ddu;  // INIT_B
  uint32_t w[8];
  for (int i = 0; i < 8; i++) {
    uint32_t v = pool[i & 3];
    v ^= hb; hb *= 0x58f38dedu; v *= hb; v ^= v >> 16;
    w[i] = v;
  }
  uint64_t sd[4];
  for (int i = 0; i < 4; i++) sd[i] = (uint64_t)w[2 * i] | ((uint64_t)w[2 * i + 1] << 32);
  unsigned __int128 initstate = (((unsigned __int128)sd[0]) << 64) | sd[1];
  unsigned __int128 initseq   = (((unsigned __int128)sd[2]) << 64) | sd[3];
  r.state = 0; r.inc = (initseq << 1) | 1;
  r.step(); r.state += initstate; r.step();
  r.has_uint32 = false; r.uinteger = 0;
}

struct Args {
  const float* pA2[6][KK];   // nu=2: l1-array row base (add q1*SS)
  const float* pB2[6][KK];   // nu=2: l2-array row base (add q2*SS)
  float        m2[6][KK];
  const float* pX3[10][KK];  // nu=3: parent's l1 factor row base
  const float* pY3[10][KK];  // nu=3: parent's l2 factor row base
  const float* pZ3[10][KK];  // nu=3: l3 row base
  float        m3[10][KK];
};

}  // namespace

// Quarter-unit buffer: all members statically accessed -> stays in VGPRs.
struct QBuf {
  f32x4 vx, vy, r0, r1, r2, r3;
  float m;
  float* po;
};

__device__ __forceinline__ void load_q(const Args& a, unsigned qd, unsigned s4,
                                       float* __restrict__ out, QBuf& b) {
  unsigned u = qd >> 2, part = qd & 3u;
  if (u < 768u) {  // nu=2 unit (t,k,q1); rows are q2 = part*4 .. part*4+3
    unsigned t = u >> 7, k = (u >> 4) & 7u, q1 = u & 15u;
    b.vx = *(const f32x4*)(a.pA2[t][k] + q1 * SS + s4);
    b.vy = (f32x4)(1.0f);  // va * 1.0 == va exactly -> rounding preserved
    const float* pr = a.pB2[t][k] + part * 4u * SS + s4;
    b.r0 = *(const f32x4*)(pr);
    b.r1 = *(const f32x4*)(pr + SS);
    b.r2 = *(const f32x4*)(pr + 2u * SS);
    b.r3 = *(const f32x4*)(pr + 3u * SS);
    b.m = a.m2[t][k];
    b.po = out + (size_t)(((t * 8u + k) * 16u + q1) * 16u + part * 4u) * SS + s4;
  } else {  // nu=3 unit (t,k,q1,q2); rows are q3 = part*4 .. part*4+3
    unsigned v = u - 768u;
    unsigned t = v >> 11, k = (v >> 8) & 7u, q1 = (v >> 4) & 15u, q2 = v & 15u;
    b.vx = *(const f32x4*)(a.pX3[t][k] + q1 * SS + s4);
    b.vy = *(const f32x4*)(a.pY3[t][k] + q2 * SS + s4);
    const float* pr = a.pZ3[t][k] + part * 4u * SS + s4;
    b.r0 = *(const f32x4*)(pr);
    b.r1 = *(const f32x4*)(pr + SS);
    b.r2 = *(const f32x4*)(pr + 2u * SS);
    b.r3 = *(const f32x4*)(pr + 3u * SS);
    b.m = a.m3[t][k];
    b.po = out + (size_t)(NU2_ROWS +
                          (((t * 8u + k) * 16u + q1) * 16u + q2) * 16u + part * 4u) * SS + s4;
  }
}

__device__ __forceinline__ void proc_q(const QBuf& b) {
  f32x4 F = b.vx * b.vy;  // nu=3: parent (x*y) rounded once; nu=2: va exactly
  *(f32x4*)(b.po)           = (F * b.r0) * b.m;
  *(f32x4*)(b.po + SS)      = (F * b.r1) * b.m;
  *(f32x4*)(b.po + 2u * SS) = (F * b.r2) * b.m;
  *(f32x4*)(b.po + 3u * SS) = (F * b.r3) * b.m;
}

__global__ __launch_bounds__(512) void le_kernel(Args a, float* __restrict__ out) {
  unsigned w = (blockIdx.x * 512u + threadIdx.x) >> 6;   // wave id, [0, 2048)
  unsigned s4 = (threadIdx.x & 63u) << 2;
  // contiguous quarter range: 84992/2048 = 41.5 -> start = (w*83)>>1
  unsigned qs = (w * 83u) >> 1;
  unsigned n = (((w + 1u) * 83u) >> 1) - qs;             // 41 or 42

  QBuf A, B;
  load_q(a, qs, s4, out, A);
  unsigned j = 0;
  for (; j + 1u < n; j += 2u) {
    load_q(a, qs + j + 1u, s4, out, B);   // prefetch BEFORE A's stores
    proc_q(A);
    if (j + 2u < n) load_q(a, qs + j + 2u, s4, out, A);  // prefetch BEFORE B's stores
    proc_q(B);
  }
  if (j < n) proc_q(A);  // odd tail (n==41)
}

extern "C" void kernel_launch(void* const* d_in, const int* in_sizes, int n_in,
                              void* d_out, int out_size, void* d_ws, size_t ws_size,
                              hipStream_t stream) {
  (void)in_sizes; (void)n_in; (void)d_ws; (void)ws_size; (void)out_size;

  // ---- rebuild the deterministic structure (host, every call; graph-safe) ----
  NpPcg64 rng;
  seed_rng0(rng);

  static const int pairs[6][2] = {{0,0},{0,1},{0,2},{1,1},{1,2},{2,2}};
  static const int trip[10][3] = {{0,0,0},{0,0,1},{0,0,2},{0,1,1},{0,1,2},
                                  {0,2,2},{1,1,1},{1,1,2},{1,2,2},{2,2,2}};
  static const int parent[10]  = {0,0,0,1,1,2,3,3,4,5};

  int   ip2[6][KK], i12[6][KK];
  float m2v[6][KK];
  for (int t = 0; t < 6; t++) {
    rng.integers(2 * pairs[t][0] + 1, ip2[t], KK);
    rng.integers(2 * pairs[t][1] + 1, i12[t], KK);
    rng.mults(m2v[t], KK);
  }
  int   ip3[10][KK], i13[10][KK];
  float m3v[10][KK];
  for (int u = 0; u < 10; u++) {
    rng.integers(KK, ip3[u], KK);
    rng.integers(2 * trip[u][2] + 1, i13[u], KK);
    rng.mults(m3v[u], KK);
  }

  const float* base[3] = {(const float*)d_in[0], (const float*)d_in[1], (const float*)d_in[2]};
  Args a;
  for (int t = 0; t < 6; t++) {
    for (int k = 0; k < KK; k++) {
      a.pA2[t][k] = base[pairs[t][0]] + (size_t)ip2[t][k] * QQ * SS;
      a.pB2[t][k] = base[pairs[t][1]] + (size_t)i12[t][k] * QQ * SS;
      a.m2[t][k]  = m2v[t][k];
    }
  }
  for (int u = 0; u < 10; u++) {
    for (int k = 0; k < KK; k++) {
      int p = parent[u], kp = ip3[u][k];
      a.pX3[u][k] = base[pairs[p][0]] + (size_t)ip2[p][kp] * QQ * SS;
      a.pY3[u][k] = base[pairs[p][1]] + (size_t)i12[p][kp] * QQ * SS;
      a.pZ3[u][k] = base[trip[u][2]] + (size_t)i13[u][k] * QQ * SS;
      a.m3[u][k]  = m3v[u][k];
    }
  }

  // 2048 waves = 256 blocks x 512 threads = 1 block/CU, 332 quarters/CU
  le_kernel<<<256, 512, 0, stream>>>(a, (float*)d_out);
}

// Round 8
// 70.866 us; speedup vs baseline: 1.2078x; 1.2078x over previous
//
#include <hip/hip_runtime.h>
#include <stdint.h>
#include <stddef.h>

// Problem constants (from the reference):
//   L_MAX=2, NU_MAX=3, K=8, Q=16, S=256
//   nu=2 tuples (6): rows [K,Q,Q]   = 2048 rows each, 6*2048  = 12288 rows
//   nu=3 tuples (10): rows [K,Q,Q,Q]= 32768 rows each, 10*32768 = 327680 rows
//   output = 339968 rows x 256 f32 = 348 MB (pure write-bound; inputs 144 KB)
//
// R8 layout: 256 blocks x 512 threads = 8 waves/block, 1 block/CU.
//   waves 0-4: one nu=3 unit (t,k,q1) each  -> 1280 units x 256 KB
//              hoist vx + vy[16] + vz[16] (33 loads), then 256 pure 1KB stores
//   waves 5-7: one nu=2 unit (t,k,q1) each  -> 768 units x 16 KB
// Every block = identical 1.328 MB of stores -> perfect CU balance under any
// block->CU mapping (fixes R6's 2:1 imbalance, keeps its load-free stream).
#define KK 8
#define QQ 16
#define SS 256
#define NU2_ROWS 12288u

typedef float f32x4 __attribute__((ext_vector_type(4)));

namespace {

// ---------- exact replication of numpy default_rng(0) ----------
struct NpPcg64 {
  unsigned __int128 state, inc;
  uint32_t uinteger;
  bool has_uint32;

  static unsigned __int128 mul128() {
    return (((unsigned __int128)2549297995355413924ULL) << 64) | 4865540595714422341ULL;
  }
  void step() { state = state * mul128() + inc; }
  uint64_t next64() {
    step();  // numpy pcg64: step THEN output (xsl-rr on new state)
    uint64_t hi = (uint64_t)(state >> 64), lo = (uint64_t)state;
    uint64_t x = hi ^ lo;
    unsigned rot = (unsigned)(state >> 122) & 63u;
    return (x >> rot) | (x << ((64u - rot) & 63u));
  }
  uint32_t next32() {
    if (has_uint32) { has_uint32 = false; return uinteger; }
    uint64_t n = next64();
    has_uint32 = true;
    uinteger = (uint32_t)(n >> 32);
    return (uint32_t)n;
  }
  double nextd() {
    return (double)(next64() >> 11) * (1.0 / 9007199254740992.0);
  }
  uint32_t lemire32(uint32_t rng) {
    uint32_t excl = rng + 1u;
    uint64_t m = (uint64_t)next32() * (uint64_t)excl;
    uint32_t leftover = (uint32_t)m;
    if (leftover < excl) {
      uint32_t threshold = (uint32_t)((0xFFFFFFFFu - rng) % excl);
      while (leftover < threshold) {
        m = (uint64_t)next32() * (uint64_t)excl;
        leftover = (uint32_t)m;
      }
    }
    return (uint32_t)(m >> 32);
  }
  void integers(int high, int* out, int n) {
    if (high <= 1) { for (int i = 0; i < n; i++) out[i] = 0; return; }
    uint32_t rng = (uint32_t)(high - 1);
    for (int i = 0; i < n; i++) out[i] = (int)lemire32(rng);
  }
  void mults(float* out, int n) {
    for (int i = 0; i < n; i++) out[i] = (float)(nextd() + 0.5);
  }
};

void seed_rng0(NpPcg64& r) {
  uint32_t pool[4];
  uint32_t hc = 0x43b0d7e5u;  // INIT_A
  auto hashmix = [&hc](uint32_t v) -> uint32_t {
    v ^= hc; hc *= 0x931e8875u; v *= hc; v ^= v >> 16; return v;
  };
  auto mix = [](uint32_t x, uint32_t y) -> uint32_t {
    uint32_t m = 0xca01f9ddu * x - 0x4973f715u * y; m ^= m >> 16; return m;
  };
  for (int i = 0; i < 4; i++) pool[i] = hashmix(0u);
  for (int is = 0; is < 4; is++)
    for (int id = 0; id < 4; id++)
      if (is != id) pool[id] = mix(pool[id], hashmix(pool[is]));
  uint32_t hb = 0x8b51f9ddu;  // INIT_B
  uint32_t w[8];
  for (int i = 0; i < 8; i++) {
    uint32_t v = pool[i & 3];
    v ^= hb; hb *= 0x58f38dedu; v *= hb; v ^= v >> 16;
    w[i] = v;
  }
  uint64_t sd[4];
  for (int i = 0; i < 4; i++) sd[i] = (uint64_t)w[2 * i] | ((uint64_t)w[2 * i + 1] << 32);
  unsigned __int128 initstate = (((unsigned __int128)sd[0]) << 64) | sd[1];
  unsigned __int128 initseq   = (((unsigned __int128)sd[2]) << 64) | sd[3];
  r.state = 0; r.inc = (initseq << 1) | 1;
  r.step(); r.state += initstate; r.step();
  r.has_uint32 = false; r.uinteger = 0;
}

struct Args {
  const float* pA2[6][KK];   // nu=2: l1-array row base (add q1*SS)
  const float* pB2[6][KK];   // nu=2: l2-array row base (add q2*SS)
  float        m2[6][KK];
  const float* pX3[10][KK];  // nu=3: parent's l1 factor row base
  const float* pY3[10][KK];  // nu=3: parent's l2 factor row base
  const float* pZ3[10][KK];  // nu=3: l3 row base
  float        m3[10][KK];
};

}  // namespace

__global__ __launch_bounds__(512) void le_kernel(Args a, float* __restrict__ out) {
  unsigned wl = threadIdx.x >> 6;          // wave within block, 0..7
  unsigned s4 = (threadIdx.x & 63u) << 2;

  if (wl < 5u) {  // nu=3 unit: u = blockIdx.x*5 + wl, in [0,1280)
    unsigned u = blockIdx.x * 5u + wl;
    unsigned t = u >> 7, k = (u >> 4) & 7u, q1 = u & 15u;
    const f32x4 vx = *(const f32x4*)(a.pX3[t][k] + q1 * SS + s4);
    const float* py = a.pY3[t][k] + s4;
    const float* pz = a.pZ3[t][k] + s4;
    f32x4 vy[16], vz[16];
#pragma unroll
    for (int i = 0; i < 16; i++) vy[i] = *(const f32x4*)(py + i * SS);
#pragma unroll
    for (int i = 0; i < 16; i++) vz[i] = *(const f32x4*)(pz + i * SS);
    float m = a.m3[t][k];
    float* po = out + (size_t)(NU2_ROWS + ((t * 8u + k) * 16u + q1) * 256u) * SS + s4;
#pragma unroll
    for (int q2 = 0; q2 < 16; q2++) {
      f32x4 xy = vx * vy[q2];  // parent = (x*y) rounded once (matches reference)
      float* pr = po + (size_t)(q2 * 16) * SS;
#pragma unroll
      for (int q3 = 0; q3 < 16; q3++) {
        f32x4 r = (xy * vz[q3]) * m;
        *(f32x4*)(pr + q3 * SS) = r;
      }
    }
  } else {  // nu=2 unit: u = blockIdx.x*3 + (wl-5), in [0,768)
    unsigned u = blockIdx.x * 3u + (wl - 5u);
    unsigned t = u >> 7, k = (u >> 4) & 7u, q1 = u & 15u;
    const f32x4 va = *(const f32x4*)(a.pA2[t][k] + q1 * SS + s4);
    const float* pb = a.pB2[t][k] + s4;
    float m = a.m2[t][k];
    float* po = out + (size_t)((t * 8u + k) * 16u + q1) * 16u * SS + s4;
#pragma unroll
    for (int q2 = 0; q2 < 16; q2++) {
      f32x4 vb = *(const f32x4*)(pb + q2 * SS);
      f32x4 r = (va * vb) * m;  // reference rounding: (A*B) then *mult
      *(f32x4*)(po + q2 * SS) = r;
    }
  }
}

extern "C" void kernel_launch(void* const* d_in, const int* in_sizes, int n_in,
                              void* d_out, int out_size, void* d_ws, size_t ws_size,
                              hipStream_t stream) {
  (void)in_sizes; (void)n_in; (void)d_ws; (void)ws_size; (void)out_size;

  // ---- rebuild the deterministic structure (host, every call; graph-safe) ----
  NpPcg64 rng;
  seed_rng0(rng);

  static const int pairs[6][2] = {{0,0},{0,1},{0,2},{1,1},{1,2},{2,2}};
  static const int trip[10][3] = {{0,0,0},{0,0,1},{0,0,2},{0,1,1},{0,1,2},
                                  {0,2,2},{1,1,1},{1,1,2},{1,2,2},{2,2,2}};
  static const int parent[10]  = {0,0,0,1,1,2,3,3,4,5};

  int   ip2[6][KK], i12[6][KK];
  float m2v[6][KK];
  for (int t = 0; t < 6; t++) {
    rng.integers(2 * pairs[t][0] + 1, ip2[t], KK);
    rng.integers(2 * pairs[t][1] + 1, i12[t], KK);
    rng.mults(m2v[t], KK);
  }
  int   ip3[10][KK], i13[10][KK];
  float m3v[10][KK];
  for (int u = 0; u < 10; u++) {
    rng.integers(KK, ip3[u], KK);
    rng.integers(2 * trip[u][2] + 1, i13[u], KK);
    rng.mults(m3v[u], KK);
  }

  const float* base[3] = {(const float*)d_in[0], (const float*)d_in[1], (const float*)d_in[2]};
  Args a;
  for (int t = 0; t < 6; t++) {
    for (int k = 0; k < KK; k++) {
      a.pA2[t][k] = base[pairs[t][0]] + (size_t)ip2[t][k] * QQ * SS;
      a.pB2[t][k] = base[pairs[t][1]] + (size_t)i12[t][k] * QQ * SS;
      a.m2[t][k]  = m2v[t][k];
    }
  }
  for (int u = 0; u < 10; u++) {
    for (int k = 0; k < KK; k++) {
      int p = parent[u], kp = ip3[u][k];
      a.pX3[u][k] = base[pairs[p][0]] + (size_t)ip2[p][kp] * QQ * SS;
      a.pY3[u][k] = base[pairs[p][1]] + (size_t)i12[p][kp] * QQ * SS;
      a.pZ3[u][k] = base[trip[u][2]] + (size_t)i13[u][k] * QQ * SS;
      a.m3[u][k]  = m3v[u][k];
    }
  }

  // 256 blocks x 512 threads: block b = {5 nu3 units, 3 nu2 units} = 1.328 MB
  le_kernel<<<256, 512, 0, stream>>>(a, (float*)d_out);
}